// Round 10
// baseline (108.987 us; speedup 1.0000x reference)
//
#include <hip/hip_runtime.h>

#define NROW 8192
#define DIM  128
#define NSEG 16                     // 16 column chunks of 512 cols
#define NBLK (64 * NSEG)            // real work = 1024 blocks
#define BIGF 1e30f

// >>> DIAGNOSTIC ROUND: grid is 2*NBLK; blocks >= NBLK redo identical work
// (benign identical-value race on posS/negS) so tile_mfma's dispatch duration
// doubles and it surfaces in rocprof's top-5 with full counters. Revert the
// grid to NBLK (and drop the bid mask) once counters are captured. <<<

typedef __attribute__((ext_vector_type(8))) short bf16x8;
typedef __attribute__((ext_vector_type(4))) float f32x4;

// ws layout (bytes):
//   [0, 2 MB)            xb2  : bf16, FRAGMENT-MAJOR: group g=row>>4 (512 groups),
//                               chunk c=0..15 (16B), slot row&15 -> every MFMA fragment
//                               load is contiguous 1KB/wave; a 64-col tile = linear 16KB
//   2MB + [0, 32 KB)     sq   : f32 row sq-norms (fp32-exact)
//   2MB + [64, 576 KB)   posS : [NSEG][NROW] f32 partial hardest-pos d^2
//   2MB + [576,1088 KB)  negS : [NSEG][NROW] f32 partial hardest-neg d^2

__device__ __forceinline__ unsigned short f2bf(float f) {
    unsigned u = __float_as_uint(f);
    unsigned r = (u + 0x7fffu + ((u >> 16) & 1u)) >> 16;   // RNE
    return (unsigned short)r;
}

// async global->LDS, 16B per lane; LDS dest wave-uniform base + lane*16
__device__ __forceinline__ void gload_lds16(const void* g, void* l) {
    __builtin_amdgcn_global_load_lds(
        (const __attribute__((address_space(1))) void*)g,
        (__attribute__((address_space(3))) void*)l, 16, 0, 0);
}

// one wave per row: bf16-convert into fragment-major layout + fp32 sq-norm
__global__ __launch_bounds__(256) void prep_kernel(const float* __restrict__ x,
                                                   unsigned short* __restrict__ xb2,
                                                   float* __restrict__ sq,
                                                   float* __restrict__ out) {
    int gtid = blockIdx.x * 256 + threadIdx.x;
    if (gtid == 0) out[0] = 0.0f;
    int row  = gtid >> 6;
    int lane = threadIdx.x & 63;
    const float* xr = x + (size_t)row * DIM;
    float a = xr[lane];
    float b = xr[lane + 64];
    // fragment-major dst: g*2048 + chunk*128 + slot*8 + within (ushort units)
    size_t d0 = (size_t)(row >> 4) * 2048 + (size_t)(lane >> 3) * 128
              + (size_t)(row & 15) * 8 + (lane & 7);
    xb2[d0]            = f2bf(a);   // elem lane      -> chunk lane>>3
    xb2[d0 + 8 * 128]  = f2bf(b);   // elem lane+64   -> chunk 8+(lane>>3)
    float s = a * a + b * b;
    #pragma unroll
    for (int o = 32; o > 0; o >>= 1) s += __shfl_down(s, o);
    if (lane == 0) sq[row] = s;
}

// v6 structure (best measured: 90.08 us total): 64 row-panels x 16 col-chunks,
// 4 waves stacked (wave owns 32 rows x 64 cols), B double-buffered 2x16KB via
// linear global_load_lds, prefetch-before-compute, one barrier per jt,
// A frags register-resident, extrema in registers, per-seg plain stores.
__global__ __launch_bounds__(256, 3) void tile_mfma(const unsigned short* __restrict__ xb2,
                                                    const int* __restrict__ lbl,
                                                    const float* __restrict__ sq,
                                                    float* __restrict__ posS,
                                                    float* __restrict__ negS) {
    __shared__ unsigned short Bs[2][64 * DIM];   // 2 x 16 KB
    const int bid = blockIdx.x & (NBLK - 1);     // DIAGNOSTIC: fold duplicate grid half
    const int rb  = bid >> 4;         // 0..63
    const int jq  = bid & 15;         // 0..15
    const int i0  = rb * 128;
    const int jbase = jq * 512;
    const int t    = threadIdx.x;
    const int lane = t & 63;
    const int w    = t >> 6;
    const int wr0  = i0 + w * 32;     // this wave's first row
    const int quad = lane >> 4;
    const int l15  = lane & 15;

    const char* xbB = (const char*)xb2;

    // ---- A fragments: 8 contiguous-1KB loads, once per block ----
    bf16x8 af[2][4];
    const int gA = wr0 >> 4;
    #pragma unroll
    for (int ti = 0; ti < 2; ti++)
        #pragma unroll
        for (int ks = 0; ks < 4; ks++)
            af[ti][ks] = *(const bf16x8*)(xb2 + (size_t)(gA + ti) * 2048 + (ks * 4 + quad) * 128 + l15 * 8);

    // per-lane row metadata
    int lbli[2][4];
    #pragma unroll
    for (int ti = 0; ti < 2; ti++) {
        int4 l4 = *(const int4*)(lbl + wr0 + ti * 16 + quad * 4);
        lbli[ti][0] = l4.x; lbli[ti][1] = l4.y; lbli[ti][2] = l4.z; lbli[ti][3] = l4.w;
    }
    // does this block's row range intersect its col range? (1 of 16 blocks per rb)
    const bool hasDiag = (i0 >= jbase) && (i0 < jbase + 512);

    float posm[2][4], negm[2][4];
    #pragma unroll
    for (int ti = 0; ti < 2; ti++)
        #pragma unroll
        for (int r = 0; r < 4; r++) { posm[ti][r] = -BIGF; negm[ti][r] = BIGF; }

    // ---- prologue: stage B tile jt=0 (linear 16KB copy) ----
    {
        const char* src = xbB + (size_t)(jbase >> 4) * 4096;
        #pragma unroll
        for (int i = 0; i < 4; i++)
            gload_lds16(src + i * 4096 + t * 16, (char*)&Bs[0][0] + i * 4096 + w * 1024);
    }
    __syncthreads();

    #pragma unroll 1
    for (int jt = 0; jt < 8; jt++) {
        const int cur = jt & 1;
        const int j0  = jbase + jt * 64;

        // prefetch next tile (latency hides under this jt's compute)
        if (jt < 7) {
            const char* src = xbB + (size_t)((j0 + 64) >> 4) * 4096;
            #pragma unroll
            for (int i = 0; i < 4; i++)
                gload_lds16(src + i * 4096 + t * 16, (char*)&Bs[cur ^ 1][0] + i * 4096 + w * 1024);
        }

        float sqj[4]; int lblj[4];
        #pragma unroll
        for (int tj = 0; tj < 4; tj++) {
            int c = j0 + tj * 16 + l15;
            sqj[tj]  = sq[c];
            lblj[tj] = lbl[c];
        }

        f32x4 acc[2][4];
        #pragma unroll
        for (int ti = 0; ti < 2; ti++)
            #pragma unroll
            for (int tj = 0; tj < 4; tj++) acc[ti][tj] = (f32x4){0.f, 0.f, 0.f, 0.f};

        #pragma unroll
        for (int ks = 0; ks < 4; ks++) {
            bf16x8 bfr[4];
            #pragma unroll
            for (int tj = 0; tj < 4; tj++)
                bfr[tj] = *(const bf16x8*)((const char*)&Bs[cur][0] + tj * 4096 + (ks * 4 + quad) * 256 + l15 * 16);
            #pragma unroll
            for (int ti = 0; ti < 2; ti++)
                #pragma unroll
                for (int tj = 0; tj < 4; tj++)
                    acc[ti][tj] = __builtin_amdgcn_mfma_f32_16x16x32_bf16(af[ti][ks], bfr[tj], acc[ti][tj], 0, 0, 0);
        }

        // epilogue: direct label compare
        #pragma unroll
        for (int ti = 0; ti < 2; ti++) {
            const int rowg = wr0 + ti * 16 + quad * 4;
            #pragma unroll
            for (int tj = 0; tj < 4; tj++) {
                const int jc = j0 + tj * 16 + l15;
                #pragma unroll
                for (int r = 0; r < 4; r++) {
                    float sr = fmaf(-2.0f, acc[ti][tj][r], sqj[tj]);
                    bool same = (lbli[ti][r] == lblj[tj]);
                    bool self = hasDiag && (jc == rowg + r);
                    posm[ti][r] = fmaxf(posm[ti][r], (same && !self) ? sr : -BIGF);
                    negm[ti][r] = fminf(negm[ti][r], same ? BIGF : sr);
                }
            }
        }

        __syncthreads();   // prefetch drained (covered by compute) + guards buffer reuse
    }

    // ---- flush: reduce across the 16 col-lanes, plain store per seg ----
    #pragma unroll
    for (int ti = 0; ti < 2; ti++)
        #pragma unroll
        for (int r = 0; r < 4; r++) {
            float p = posm[ti][r];
            float n = negm[ti][r];
            #pragma unroll
            for (int m = 8; m >= 1; m >>= 1) {
                p = fmaxf(p, __shfl_xor(p, m));
                n = fminf(n, __shfl_xor(n, m));
            }
            if (l15 == 0) {
                int row = wr0 + ti * 16 + quad * 4 + r;
                float sqi = sq[row];
                posS[jq * NROW + row] = fmaxf(0.0f, sqi + p);   // -BIG -> 0 (no positive here)
                negS[jq * NROW + row] = fmaxf(0.0f, sqi + n);   // clamp bf16-noise negatives
            }
        }
}

__global__ __launch_bounds__(256) void tri_final(const float* __restrict__ posS,
                                                 const float* __restrict__ negS,
                                                 const float* __restrict__ margin,
                                                 float* __restrict__ out) {
    int r = blockIdx.x * 256 + threadIdx.x;
    float p = 0.0f, n = BIGF;
    #pragma unroll
    for (int q = 0; q < NSEG; q++) {
        p = fmaxf(p, posS[q * NROW + r]);
        n = fminf(n, negS[q * NROW + r]);
    }
    float m = margin[0];
    float loss = fmaxf(sqrtf(p) - sqrtf(n) + m, 0.0f) * (1.0f / (float)NROW);
    #pragma unroll
    for (int o = 32; o > 0; o >>= 1) loss += __shfl_down(loss, o);
    __shared__ float wsum[4];
    int lane = threadIdx.x & 63, wv = threadIdx.x >> 6;
    if (lane == 0) wsum[wv] = loss;
    __syncthreads();
    if (threadIdx.x == 0) atomicAdd(out, wsum[0] + wsum[1] + wsum[2] + wsum[3]);
}

extern "C" void kernel_launch(void* const* d_in, const int* in_sizes, int n_in,
                              void* d_out, int out_size, void* d_ws, size_t ws_size,
                              hipStream_t stream) {
    const float* x      = (const float*)d_in[0];
    const int*   lbl    = (const int*)d_in[1];
    const float* margin = (const float*)d_in[2];
    float* out = (float*)d_out;

    char* ws = (char*)d_ws;
    unsigned short* xb2 = (unsigned short*)ws;
    float* sq   = (float*)(ws + (2u << 20));
    float* posS = (float*)(ws + (2u << 20) + (64u << 10));
    float* negS = (float*)(ws + (2u << 20) + (576u << 10));

    prep_kernel<<<2048, 256, 0, stream>>>(x, xb2, sq, out);
    tile_mfma<<<NBLK * 2, 256, 0, stream>>>(xb2, lbl, sq, posS, negS);   // DIAGNOSTIC x2
    tri_final<<<NROW / 256, 256, 0, stream>>>(posS, negS, margin, out);
}

// Round 12
// 108.401 us; speedup vs baseline: 1.0054x; 1.0054x over previous
//
#include <hip/hip_runtime.h>

#define NROW 8192
#define DIM  128
#define NLBL 512
#define NSEG 16                     // 16 column chunks of 512 cols
#define NBLK (64 * NSEG)            // 1024 Gram blocks
#define BIGF 1e30f

typedef __attribute__((ext_vector_type(8))) short bf16x8;
typedef __attribute__((ext_vector_type(4))) float f32x4;

// ws layout (bytes):
//   [0, 2 MB)             xb2     : bf16, FRAGMENT-MAJOR, SORTED row order: group
//                                   g=slot>>4, chunk c (16B), slot&15 -> 1KB/frag
//   2MB + [0,  32 KB)     sq      : f32 row sq-norms (sorted order)
//   2MB + [32, 64 KB)     rowBand : u32 = binLo | binHi<<16 (sorted-space label band)
//   2MB + [64, 96 KB)     lblS    : i32 sorted labels
//   2MB + [96 KB, +2052)  binStart: 513 i32
//   2MB + [100 KB, +2048) cursor  : 512 u32
//   2MB + [104 KB, +2048) hist    : 512 i32 (zeroed by zero_hist kernel)
//   2MB + [128, 640 KB)   posS    : [NSEG][NROW] f32 partial hardest-pos d^2
//   2MB + [640,1152 KB)   negS    : [NSEG][NROW] f32 partial hardest-neg d^2

__device__ __forceinline__ unsigned short f2bf(float f) {
    unsigned u = __float_as_uint(f);
    unsigned r = (u + 0x7fffu + ((u >> 16) & 1u)) >> 16;   // RNE
    return (unsigned short)r;
}

// async global->LDS, 16B per lane; LDS dest wave-uniform base + lane*16
__device__ __forceinline__ void gload_lds16(const void* g, void* l) {
    __builtin_amdgcn_global_load_lds(
        (const __attribute__((address_space(1))) void*)g,
        (__attribute__((address_space(3))) void*)l, 16, 0, 0);
}

// 1 block: zero the histogram (replaces hipMemsetAsync — graph-capture-safe by
// construction; the memset was the only new API in the container-failed round).
__global__ __launch_bounds__(512) void zero_hist(int* __restrict__ hist) {
    hist[threadIdx.x] = 0;
}

// 8192 threads: parallel label histogram via device atomics (hist pre-zeroed).
__global__ __launch_bounds__(256) void hist_kernel(const int* __restrict__ lbl,
                                                   int* __restrict__ hist) {
    int i = blockIdx.x * 256 + threadIdx.x;
    atomicAdd(&hist[lbl[i]], 1);
}

// 1 block, 512 threads: exclusive scan of hist -> binStart/cursor.
__global__ __launch_bounds__(512) void scan_kernel(const int* __restrict__ hist,
                                                   int* __restrict__ binStart,
                                                   unsigned* __restrict__ cursor,
                                                   float* __restrict__ out) {
    __shared__ int sc[NLBL];
    const int t = threadIdx.x;
    int h = hist[t];
    sc[t] = h;
    __syncthreads();
    for (int off = 1; off < NLBL; off <<= 1) {
        int v = (t >= off) ? sc[t - off] : 0;
        __syncthreads();
        sc[t] += v;
        __syncthreads();
    }
    int st = sc[t] - h;              // exclusive prefix
    binStart[t] = st;
    cursor[t]   = (unsigned)st;
    if (t == 0) { binStart[NLBL] = NROW; out[0] = 0.0f; }
}

// 16 lanes per row: bf16-convert + scatter to sorted slot (ONE uint4 store per
// thread — v6's 2B scattered stores cost ~15us; this pattern measured ~3-4us),
// fp32 sq-norm, sorted labels, and the row's band [binStart[l], binStart[l+1]).
__global__ __launch_bounds__(256) void prep_scatter(const float* __restrict__ x,
                                                    const int* __restrict__ lbl,
                                                    const int* __restrict__ binStart,
                                                    unsigned* __restrict__ cursor,
                                                    unsigned short* __restrict__ xb2,
                                                    float* __restrict__ sq,
                                                    unsigned* __restrict__ rowBand,
                                                    int* __restrict__ lblS) {
    const int t   = threadIdx.x;
    const int row = blockIdx.x * 16 + (t >> 4);
    const int c   = t & 15;                     // 16B chunk of the row
    const float* xr = x + (size_t)row * DIM + c * 8;
    float4 f0 = *(const float4*)xr;
    float4 f1 = *(const float4*)(xr + 4);
    float s = f0.x*f0.x + f0.y*f0.y + f0.z*f0.z + f0.w*f0.w
            + f1.x*f1.x + f1.y*f1.y + f1.z*f1.z + f1.w*f1.w;
    #pragma unroll
    for (int m = 1; m <= 8; m <<= 1) s += __shfl_xor(s, m);   // stays in 16-group
    const int l = lbl[row];
    unsigned p = 0;
    if (c == 0) p = atomicAdd(&cursor[l], 1u);  // sorted destination slot
    p = __shfl((int)p, t & 48);                 // broadcast within the 16-group
    unsigned w0 = (unsigned)f2bf(f0.x) | ((unsigned)f2bf(f0.y) << 16);
    unsigned w1 = (unsigned)f2bf(f0.z) | ((unsigned)f2bf(f0.w) << 16);
    unsigned w2 = (unsigned)f2bf(f1.x) | ((unsigned)f2bf(f1.y) << 16);
    unsigned w3 = (unsigned)f2bf(f1.z) | ((unsigned)f2bf(f1.w) << 16);
    uint4 v = make_uint4(w0, w1, w2, w3);
    *(uint4*)(xb2 + (size_t)(p >> 4) * 2048 + c * 128 + (p & 15) * 8) = v;
    if (c == 0) {
        sq[p]      = s;
        lblS[p]    = l;
        rowBand[p] = (unsigned)binStart[l] | ((unsigned)binStart[l + 1] << 16);
    }
}

// v6 structure (counter-verified: VALU 54% / MFMA 28% / stalls 18%, conflicts 0)
// with the ONE change the counters demand: sorted-band wave-uniform fast path
// cuts the dominant VALU term — ~90% of 16-col subtiles take 2 ops/elem
// (pure-negative fma+min) selected by a scalar envelope test; slow path is
// v6's exact label-compare code. Everything else untouched.
__global__ __launch_bounds__(256, 3) void tile_mfma(const unsigned short* __restrict__ xb2,
                                                    const int* __restrict__ lblS,
                                                    const float* __restrict__ sq,
                                                    const unsigned* __restrict__ rowBand,
                                                    float* __restrict__ posS,
                                                    float* __restrict__ negS) {
    __shared__ unsigned short Bs[2][64 * DIM];   // 2 x 16 KB
    const int bid = blockIdx.x;
    const int rb  = bid >> 4;         // 0..63
    const int jq  = bid & 15;         // 0..15
    const int i0  = rb * 128;
    const int jbase = jq * 512;
    const int t    = threadIdx.x;
    const int lane = t & 63;
    const int w    = t >> 6;
    const int wr0  = i0 + w * 32;     // this wave's first (sorted) row
    const int quad = lane >> 4;
    const int l15  = lane & 15;

    const char* xbB = (const char*)xb2;

    // ---- A fragments: 8 contiguous-1KB loads, once per block ----
    bf16x8 af[2][4];
    const int gA = wr0 >> 4;
    #pragma unroll
    for (int ti = 0; ti < 2; ti++)
        #pragma unroll
        for (int ks = 0; ks < 4; ks++)
            af[ti][ks] = *(const bf16x8*)(xb2 + (size_t)(gA + ti) * 2048 + (ks * 4 + quad) * 128 + l15 * 8);

    // per-lane row metadata (sorted space)
    int lbli[2][4];
    #pragma unroll
    for (int ti = 0; ti < 2; ti++) {
        int4 l4 = *(const int4*)(lblS + wr0 + ti * 16 + quad * 4);
        lbli[ti][0] = l4.x; lbli[ti][1] = l4.y; lbli[ti][2] = l4.z; lbli[ti][3] = l4.w;
    }
    // wave-uniform band envelope per ti (16 sorted rows => tight)
    int tiLo[2], tiHi[2];
    #pragma unroll
    for (int ti = 0; ti < 2; ti++) {
        uint4 b4 = *(const uint4*)(rowBand + wr0 + ti * 16 + quad * 4);
        int lo = (int)(b4.x & 0xffffu), hi = (int)(b4.x >> 16);
        lo = min(lo, (int)(b4.y & 0xffffu)); hi = max(hi, (int)(b4.y >> 16));
        lo = min(lo, (int)(b4.z & 0xffffu)); hi = max(hi, (int)(b4.z >> 16));
        lo = min(lo, (int)(b4.w & 0xffffu)); hi = max(hi, (int)(b4.w >> 16));
        int v;
        v = __shfl_xor(lo, 16); lo = min(lo, v);
        v = __shfl_xor(lo, 32); lo = min(lo, v);
        v = __shfl_xor(hi, 16); hi = max(hi, v);
        v = __shfl_xor(hi, 32); hi = max(hi, v);
        tiLo[ti] = __builtin_amdgcn_readfirstlane(lo);
        tiHi[ti] = __builtin_amdgcn_readfirstlane(hi);
    }

    float posm[2][4], negm[2][4];
    #pragma unroll
    for (int ti = 0; ti < 2; ti++)
        #pragma unroll
        for (int r = 0; r < 4; r++) { posm[ti][r] = -BIGF; negm[ti][r] = BIGF; }

    // ---- prologue: stage B tile jt=0 (linear 16KB copy) ----
    {
        const char* src = xbB + (size_t)(jbase >> 4) * 4096;
        #pragma unroll
        for (int i = 0; i < 4; i++)
            gload_lds16(src + i * 4096 + t * 16, (char*)&Bs[0][0] + i * 4096 + w * 1024);
    }
    __syncthreads();

    #pragma unroll 1
    for (int jt = 0; jt < 8; jt++) {
        const int cur = jt & 1;
        const int j0  = jbase + jt * 64;

        // prefetch next tile (latency hides under this jt's compute)
        if (jt < 7) {
            const char* src = xbB + (size_t)((j0 + 64) >> 4) * 4096;
            #pragma unroll
            for (int i = 0; i < 4; i++)
                gload_lds16(src + i * 4096 + t * 16, (char*)&Bs[cur ^ 1][0] + i * 4096 + w * 1024);
        }

        float sqj[4]; int lblj[4];
        #pragma unroll
        for (int tj = 0; tj < 4; tj++) {
            int c = j0 + tj * 16 + l15;
            sqj[tj]  = sq[c];
            lblj[tj] = lblS[c];
        }

        f32x4 acc[2][4];
        #pragma unroll
        for (int ti = 0; ti < 2; ti++)
            #pragma unroll
            for (int tj = 0; tj < 4; tj++) acc[ti][tj] = (f32x4){0.f, 0.f, 0.f, 0.f};

        #pragma unroll
        for (int ks = 0; ks < 4; ks++) {
            bf16x8 bfr[4];
            #pragma unroll
            for (int tj = 0; tj < 4; tj++)
                bfr[tj] = *(const bf16x8*)((const char*)&Bs[cur][0] + tj * 4096 + (ks * 4 + quad) * 256 + l15 * 16);
            #pragma unroll
            for (int ti = 0; ti < 2; ti++)
                #pragma unroll
                for (int tj = 0; tj < 4; tj++)
                    acc[ti][tj] = __builtin_amdgcn_mfma_f32_16x16x32_bf16(af[ti][ks], bfr[tj], acc[ti][tj], 0, 0, 0);
        }

        // ---- epilogue: wave-uniform band fast/slow split ----
        #pragma unroll
        for (int ti = 0; ti < 2; ti++) {
            const int rowg = wr0 + ti * 16 + quad * 4;
            #pragma unroll
            for (int tj = 0; tj < 4; tj++) {
                const int colLo = j0 + tj * 16;
                if (colLo + 16 <= tiLo[ti] || colLo >= tiHi[ti]) {
                    // no same-label pair possible: pure negatives, 2 ops/elem
                    #pragma unroll
                    for (int r = 0; r < 4; r++) {
                        float sr = fmaf(-2.0f, acc[ti][tj][r], sqj[tj]);
                        negm[ti][r] = fminf(negm[ti][r], sr);
                    }
                } else {
                    const int jc = colLo + l15;
                    #pragma unroll
                    for (int r = 0; r < 4; r++) {
                        float sr = fmaf(-2.0f, acc[ti][tj][r], sqj[tj]);
                        bool same = (lbli[ti][r] == lblj[tj]);
                        bool self = (jc == rowg + r);   // sorted-global diagonal
                        posm[ti][r] = fmaxf(posm[ti][r], (same && !self) ? sr : -BIGF);
                        negm[ti][r] = fminf(negm[ti][r], same ? BIGF : sr);
                    }
                }
            }
        }

        __syncthreads();   // prefetch drained (covered by compute) + guards buffer reuse
    }

    // ---- flush: reduce across the 16 col-lanes, plain store per seg ----
    #pragma unroll
    for (int ti = 0; ti < 2; ti++)
        #pragma unroll
        for (int r = 0; r < 4; r++) {
            float p = posm[ti][r];
            float n = negm[ti][r];
            #pragma unroll
            for (int m = 8; m >= 1; m >>= 1) {
                p = fmaxf(p, __shfl_xor(p, m));
                n = fminf(n, __shfl_xor(n, m));
            }
            if (l15 == 0) {
                int row = wr0 + ti * 16 + quad * 4 + r;
                float sqi = sq[row];
                posS[jq * NROW + row] = fmaxf(0.0f, sqi + p);   // -BIG -> 0 (no positive here)
                negS[jq * NROW + row] = fmaxf(0.0f, sqi + n);   // clamp bf16-noise negatives
            }
        }
}

__global__ __launch_bounds__(256) void tri_final(const float* __restrict__ posS,
                                                 const float* __restrict__ negS,
                                                 const float* __restrict__ margin,
                                                 float* __restrict__ out) {
    int r = blockIdx.x * 256 + threadIdx.x;
    float p = 0.0f, n = BIGF;
    #pragma unroll
    for (int q = 0; q < NSEG; q++) {
        p = fmaxf(p, posS[q * NROW + r]);
        n = fminf(n, negS[q * NROW + r]);
    }
    float m = margin[0];
    float loss = fmaxf(sqrtf(p) - sqrtf(n) + m, 0.0f) * (1.0f / (float)NROW);
    #pragma unroll
    for (int o = 32; o > 0; o >>= 1) loss += __shfl_down(loss, o);
    __shared__ float wsum[4];
    int lane = threadIdx.x & 63, wv = threadIdx.x >> 6;
    if (lane == 0) wsum[wv] = loss;
    __syncthreads();
    if (threadIdx.x == 0) atomicAdd(out, wsum[0] + wsum[1] + wsum[2] + wsum[3]);
}

extern "C" void kernel_launch(void* const* d_in, const int* in_sizes, int n_in,
                              void* d_out, int out_size, void* d_ws, size_t ws_size,
                              hipStream_t stream) {
    const float* x      = (const float*)d_in[0];
    const int*   lbl    = (const int*)d_in[1];
    const float* margin = (const float*)d_in[2];
    float* out = (float*)d_out;

    char* ws = (char*)d_ws;
    unsigned short* xb2 = (unsigned short*)ws;
    float*    sq       = (float*)(ws + (2u << 20));
    unsigned* rowBand  = (unsigned*)(ws + (2u << 20) + (32u << 10));
    int*      lblS     = (int*)(ws + (2u << 20) + (64u << 10));
    int*      binStart = (int*)(ws + (2u << 20) + (96u << 10));
    unsigned* cursor   = (unsigned*)(ws + (2u << 20) + (100u << 10));
    int*      hist     = (int*)(ws + (2u << 20) + (104u << 10));
    float*    posS     = (float*)(ws + (2u << 20) + (128u << 10));
    float*    negS     = (float*)(ws + (2u << 20) + (640u << 10));

    zero_hist<<<1, 512, 0, stream>>>(hist);
    hist_kernel<<<NROW / 256, 256, 0, stream>>>(lbl, hist);
    scan_kernel<<<1, 512, 0, stream>>>(hist, binStart, cursor, out);
    prep_scatter<<<NROW / 16, 256, 0, stream>>>(x, lbl, binStart, cursor, xb2, sq, rowBand, lblS);
    tile_mfma<<<NBLK, 256, 0, stream>>>(xb2, lblS, sq, rowBand, posS, negS);
    tri_final<<<NROW / 256, 256, 0, stream>>>(posS, negS, margin, out);
}

// Round 13
// 87.901 us; speedup vs baseline: 1.2399x; 1.2332x over previous
//
#include <hip/hip_runtime.h>

#define NROW 8192
#define DIM  128
#define NSEG 16                     // 16 column chunks of 512 cols
#define NBLK (64 * NSEG)            // 1024 Gram blocks
#define BIGF 1e30f

typedef __attribute__((ext_vector_type(8))) short bf16x8;
typedef __attribute__((ext_vector_type(4))) float f32x4;

// ws layout (bytes):
//   [0, 2 MB)            xb2  : bf16, FRAGMENT-MAJOR: group g=row>>4 (512 groups),
//                               chunk c=0..15 (16B), slot row&15 -> every MFMA fragment
//                               load is contiguous 1KB/wave; a 64-col tile = linear 16KB
//   2MB + [0, 32 KB)     sq   : f32 row sq-norms (fp32-exact)
//   2MB + [64, 576 KB)   posS : [NSEG][NROW] f32 partial hardest-pos d^2
//   2MB + [576,1088 KB)  negS : [NSEG][NROW] f32 partial hardest-neg d^2

__device__ __forceinline__ unsigned short f2bf(float f) {
    unsigned u = __float_as_uint(f);
    unsigned r = (u + 0x7fffu + ((u >> 16) & 1u)) >> 16;   // RNE
    return (unsigned short)r;
}

// async global->LDS, 16B per lane; LDS dest wave-uniform base + lane*16
__device__ __forceinline__ void gload_lds16(const void* g, void* l) {
    __builtin_amdgcn_global_load_lds(
        (const __attribute__((address_space(1))) void*)g,
        (__attribute__((address_space(3))) void*)l, 16, 0, 0);
}

// 16 lanes per row, ONE uint4 store per thread (v6's two scattered 2B stores
// per thread measured ~15us total; this store pattern measured ~2.5-3.5us in
// v4/v8 — here WITHOUT the sort chain that made those variants net losers).
__global__ __launch_bounds__(256) void prep_kernel(const float* __restrict__ x,
                                                   unsigned short* __restrict__ xb2,
                                                   float* __restrict__ sq,
                                                   float* __restrict__ out) {
    const int t   = threadIdx.x;
    const int row = blockIdx.x * 16 + (t >> 4);
    const int c   = t & 15;                     // 16B chunk of the row
    if (blockIdx.x == 0 && t == 0) out[0] = 0.0f;
    const float* xr = x + (size_t)row * DIM + c * 8;
    float4 f0 = *(const float4*)xr;
    float4 f1 = *(const float4*)(xr + 4);
    float s = f0.x*f0.x + f0.y*f0.y + f0.z*f0.z + f0.w*f0.w
            + f1.x*f1.x + f1.y*f1.y + f1.z*f1.z + f1.w*f1.w;
    #pragma unroll
    for (int m = 1; m <= 8; m <<= 1) s += __shfl_xor(s, m);   // stays in 16-group
    unsigned w0 = (unsigned)f2bf(f0.x) | ((unsigned)f2bf(f0.y) << 16);
    unsigned w1 = (unsigned)f2bf(f0.z) | ((unsigned)f2bf(f0.w) << 16);
    unsigned w2 = (unsigned)f2bf(f1.x) | ((unsigned)f2bf(f1.y) << 16);
    unsigned w3 = (unsigned)f2bf(f1.z) | ((unsigned)f2bf(f1.w) << 16);
    uint4 v = make_uint4(w0, w1, w2, w3);
    *(uint4*)(xb2 + (size_t)(row >> 4) * 2048 + c * 128 + (row & 15) * 8) = v;
    if (c == 0) sq[row] = s;
}

// v6 tile, byte-identical (counter-verified round 10: VALU 54% / MFMA 28% /
// stalls ~18%, conflicts 0, occupancy 33.8%, VGPR 64): 64 row-panels x 16
// col-chunks, 4 waves stacked (wave owns 32 rows x 64 cols), B double-buffered
// 2x16KB via linear global_load_lds, prefetch-before-compute, one barrier per
// jt, A frags register-resident, extrema in registers, per-seg plain stores.
__global__ __launch_bounds__(256, 3) void tile_mfma(const unsigned short* __restrict__ xb2,
                                                    const int* __restrict__ lbl,
                                                    const float* __restrict__ sq,
                                                    float* __restrict__ posS,
                                                    float* __restrict__ negS) {
    __shared__ unsigned short Bs[2][64 * DIM];   // 2 x 16 KB
    const int bid = blockIdx.x;
    const int rb  = bid >> 4;         // 0..63
    const int jq  = bid & 15;         // 0..15
    const int i0  = rb * 128;
    const int jbase = jq * 512;
    const int t    = threadIdx.x;
    const int lane = t & 63;
    const int w    = t >> 6;
    const int wr0  = i0 + w * 32;     // this wave's first row
    const int quad = lane >> 4;
    const int l15  = lane & 15;

    const char* xbB = (const char*)xb2;

    // ---- A fragments: 8 contiguous-1KB loads, once per block ----
    bf16x8 af[2][4];
    const int gA = wr0 >> 4;
    #pragma unroll
    for (int ti = 0; ti < 2; ti++)
        #pragma unroll
        for (int ks = 0; ks < 4; ks++)
            af[ti][ks] = *(const bf16x8*)(xb2 + (size_t)(gA + ti) * 2048 + (ks * 4 + quad) * 128 + l15 * 8);

    // per-lane row metadata
    int lbli[2][4];
    #pragma unroll
    for (int ti = 0; ti < 2; ti++) {
        int4 l4 = *(const int4*)(lbl + wr0 + ti * 16 + quad * 4);
        lbli[ti][0] = l4.x; lbli[ti][1] = l4.y; lbli[ti][2] = l4.z; lbli[ti][3] = l4.w;
    }
    // does this block's row range intersect its col range? (1 of 16 blocks per rb)
    const bool hasDiag = (i0 >= jbase) && (i0 < jbase + 512);

    float posm[2][4], negm[2][4];
    #pragma unroll
    for (int ti = 0; ti < 2; ti++)
        #pragma unroll
        for (int r = 0; r < 4; r++) { posm[ti][r] = -BIGF; negm[ti][r] = BIGF; }

    // ---- prologue: stage B tile jt=0 (linear 16KB copy) ----
    {
        const char* src = xbB + (size_t)(jbase >> 4) * 4096;
        #pragma unroll
        for (int i = 0; i < 4; i++)
            gload_lds16(src + i * 4096 + t * 16, (char*)&Bs[0][0] + i * 4096 + w * 1024);
    }
    __syncthreads();

    #pragma unroll 1
    for (int jt = 0; jt < 8; jt++) {
        const int cur = jt & 1;
        const int j0  = jbase + jt * 64;

        // prefetch next tile (latency hides under this jt's compute)
        if (jt < 7) {
            const char* src = xbB + (size_t)((j0 + 64) >> 4) * 4096;
            #pragma unroll
            for (int i = 0; i < 4; i++)
                gload_lds16(src + i * 4096 + t * 16, (char*)&Bs[cur ^ 1][0] + i * 4096 + w * 1024);
        }

        float sqj[4]; int lblj[4];
        #pragma unroll
        for (int tj = 0; tj < 4; tj++) {
            int c = j0 + tj * 16 + l15;
            sqj[tj]  = sq[c];
            lblj[tj] = lbl[c];
        }

        f32x4 acc[2][4];
        #pragma unroll
        for (int ti = 0; ti < 2; ti++)
            #pragma unroll
            for (int tj = 0; tj < 4; tj++) acc[ti][tj] = (f32x4){0.f, 0.f, 0.f, 0.f};

        #pragma unroll
        for (int ks = 0; ks < 4; ks++) {
            bf16x8 bfr[4];
            #pragma unroll
            for (int tj = 0; tj < 4; tj++)
                bfr[tj] = *(const bf16x8*)((const char*)&Bs[cur][0] + tj * 4096 + (ks * 4 + quad) * 256 + l15 * 16);
            #pragma unroll
            for (int ti = 0; ti < 2; ti++)
                #pragma unroll
                for (int tj = 0; tj < 4; tj++)
                    acc[ti][tj] = __builtin_amdgcn_mfma_f32_16x16x32_bf16(af[ti][ks], bfr[tj], acc[ti][tj], 0, 0, 0);
        }

        // epilogue: direct label compare
        #pragma unroll
        for (int ti = 0; ti < 2; ti++) {
            const int rowg = wr0 + ti * 16 + quad * 4;
            #pragma unroll
            for (int tj = 0; tj < 4; tj++) {
                const int jc = j0 + tj * 16 + l15;
                #pragma unroll
                for (int r = 0; r < 4; r++) {
                    float sr = fmaf(-2.0f, acc[ti][tj][r], sqj[tj]);
                    bool same = (lbli[ti][r] == lblj[tj]);
                    bool self = hasDiag && (jc == rowg + r);
                    posm[ti][r] = fmaxf(posm[ti][r], (same && !self) ? sr : -BIGF);
                    negm[ti][r] = fminf(negm[ti][r], same ? BIGF : sr);
                }
            }
        }

        __syncthreads();   // prefetch drained (covered by compute) + guards buffer reuse
    }

    // ---- flush: reduce across the 16 col-lanes, plain store per seg ----
    #pragma unroll
    for (int ti = 0; ti < 2; ti++)
        #pragma unroll
        for (int r = 0; r < 4; r++) {
            float p = posm[ti][r];
            float n = negm[ti][r];
            #pragma unroll
            for (int m = 8; m >= 1; m >>= 1) {
                p = fmaxf(p, __shfl_xor(p, m));
                n = fminf(n, __shfl_xor(n, m));
            }
            if (l15 == 0) {
                int row = wr0 + ti * 16 + quad * 4 + r;
                float sqi = sq[row];
                posS[jq * NROW + row] = fmaxf(0.0f, sqi + p);   // -BIG -> 0 (no positive here)
                negS[jq * NROW + row] = fmaxf(0.0f, sqi + n);   // clamp bf16-noise negatives
            }
        }
}

__global__ __launch_bounds__(256) void tri_final(const float* __restrict__ posS,
                                                 const float* __restrict__ negS,
                                                 const float* __restrict__ margin,
                                                 float* __restrict__ out) {
    int r = blockIdx.x * 256 + threadIdx.x;
    float p = 0.0f, n = BIGF;
    #pragma unroll
    for (int q = 0; q < NSEG; q++) {
        p = fmaxf(p, posS[q * NROW + r]);
        n = fminf(n, negS[q * NROW + r]);
    }
    float m = margin[0];
    float loss = fmaxf(sqrtf(p) - sqrtf(n) + m, 0.0f) * (1.0f / (float)NROW);
    #pragma unroll
    for (int o = 32; o > 0; o >>= 1) loss += __shfl_down(loss, o);
    __shared__ float wsum[4];
    int lane = threadIdx.x & 63, wv = threadIdx.x >> 6;
    if (lane == 0) wsum[wv] = loss;
    __syncthreads();
    if (threadIdx.x == 0) atomicAdd(out, wsum[0] + wsum[1] + wsum[2] + wsum[3]);
}

extern "C" void kernel_launch(void* const* d_in, const int* in_sizes, int n_in,
                              void* d_out, int out_size, void* d_ws, size_t ws_size,
                              hipStream_t stream) {
    const float* x      = (const float*)d_in[0];
    const int*   lbl    = (const int*)d_in[1];
    const float* margin = (const float*)d_in[2];
    float* out = (float*)d_out;

    char* ws = (char*)d_ws;
    unsigned short* xb2 = (unsigned short*)ws;
    float* sq   = (float*)(ws + (2u << 20));
    float* posS = (float*)(ws + (2u << 20) + (64u << 10));
    float* negS = (float*)(ws + (2u << 20) + (576u << 10));

    prep_kernel<<<NROW / 16, 256, 0, stream>>>(x, xb2, sq, out);
    tile_mfma<<<NBLK, 256, 0, stream>>>(xb2, lbl, sq, posS, negS);
    tri_final<<<NROW / 256, 256, 0, stream>>>(posS, negS, margin, out);
}